// Round 4
// baseline (241.499 us; speedup 1.0000x reference)
//
#include <hip/hip_runtime.h>
#include <hip/hip_bf16.h>

typedef __bf16 bf16_t;
typedef __bf16 bf16x8 __attribute__((ext_vector_type(8)));
typedef float f32x4 __attribute__((ext_vector_type(4)));

#define NTOK 49152   // s*h*w = 3*128*128 tokens per batch
#define CDIM 128
#define CHUNKS 256   // split-K chunks for the Gram
#define KT 192       // tokens per chunk
#define STEPS 6      // KT/32

// 8 consecutive fp32 -> bf16x8
__device__ inline bf16x8 load8_f32(const float* p) {
  f32x4 a = *(const f32x4*)p;
  f32x4 b = *(const f32x4*)(p + 4);
  bf16x8 r;
  r[0] = (bf16_t)a[0]; r[1] = (bf16_t)a[1]; r[2] = (bf16_t)a[2]; r[3] = (bf16_t)a[3];
  r[4] = (bf16_t)b[0]; r[5] = (bf16_t)b[1]; r[6] = (bf16_t)b[2]; r[7] = (bf16_t)b[3];
  return r;
}

// ---------------------------------------------------------------------------
// K1: per-batch token Gram S = X X^T, split-K fp32 partials.
// grid 1024 = b(2) x chunk(256) x rowhalf(2). Each block: 64 out rows x 128
// cols over a 192-token chunk. Software-pipelined: prefetch next step's
// fragments during MFMA. A-frag re-loaded (L1-hit) to avoid runtime register
// indexing.
// ---------------------------------------------------------------------------
__global__ __launch_bounds__(256) void k1_gram(const float* __restrict__ x,
                                               float* __restrict__ part) {
  const int blk = blockIdx.x;
  const int b = blk >> 9, chunk = (blk >> 1) & 255, half = blk & 1;
  const float* Xb = x + (size_t)b * CDIM * NTOK;
  const int tid = threadIdx.x, wave = tid >> 6, lane = tid & 63;
  const int r = lane & 15, quad = lane >> 4;
  const int arow = (half * 4 + wave) * 16 + r;  // this wave's A rows

  f32x4 acc[8];
#pragma unroll
  for (int j = 0; j < 8; ++j) acc[j] = (f32x4){0.f, 0.f, 0.f, 0.f};

  const int k0 = chunk * KT + quad * 8;
  bf16x8 cur[8], nxt[8], acur, anxt;
#pragma unroll
  for (int g = 0; g < 8; ++g)
    cur[g] = load8_f32(Xb + (size_t)(16 * g + r) * NTOK + k0);
  acur = load8_f32(Xb + (size_t)arow * NTOK + k0);

#pragma unroll
  for (int step = 0; step < STEPS; ++step) {
    if (step + 1 < STEPS) {
      const int kc = k0 + (step + 1) * 32;
#pragma unroll
      for (int g = 0; g < 8; ++g)
        nxt[g] = load8_f32(Xb + (size_t)(16 * g + r) * NTOK + kc);
      anxt = load8_f32(Xb + (size_t)arow * NTOK + kc);
    }
#pragma unroll
    for (int j = 0; j < 8; ++j)
      acc[j] = __builtin_amdgcn_mfma_f32_16x16x32_bf16(acur, cur[j], acc[j], 0, 0, 0);
#pragma unroll
    for (int g = 0; g < 8; ++g) cur[g] = nxt[g];
    acur = anxt;
  }

  float* pb = part + ((size_t)(b * CHUNKS + chunk) << 14);
#pragma unroll
  for (int j = 0; j < 8; ++j) {
#pragma unroll
    for (int reg = 0; reg < 4; ++reg) {
      const int row = half * 64 + wave * 16 + quad * 4 + reg;  // C/D: row=quad*4+reg
      const int col = 16 * j + r;                               // col=lane&15
      pb[row * 128 + col] = acc[j][reg];
    }
  }
}

// ---------------------------------------------------------------------------
// K2a: reduce 256 chunks -> 8 slice-partials. grid 1024, fully coalesced.
// ---------------------------------------------------------------------------
__global__ __launch_bounds__(256) void k2a_reduce(const float* __restrict__ part,
                                                  float* __restrict__ part2) {
  const int gid = blockIdx.x * 256 + threadIdx.x;  // 0..262143
  const int slice = gid >> 15, rest = gid & 32767;
  const int b = rest >> 14, elem = rest & 16383;
  const float* p = part + ((size_t)(b * CHUNKS + slice * 32) << 14) + elem;
  float s = 0.f;
#pragma unroll 8
  for (int i = 0; i < 32; ++i) s += p[(size_t)i << 14];
  part2[((size_t)(b * 8 + slice) << 14) + elem] = s;
}

// ---------------------------------------------------------------------------
// K3a: merged T+attn. One block per (b,head). Stages S (summing the 8 slice
// partials) into padded LDS, computes Tk/Tq rows for this head, then
// G = Wk S Wq^T, norms from diagonals, softmax -> attn.
// ---------------------------------------------------------------------------
__global__ __launch_bounds__(256) void k3_ta(const float* __restrict__ part2,
                                             const float* __restrict__ Wk,
                                             const float* __restrict__ Wq,
                                             const float* __restrict__ resc,
                                             float* __restrict__ attn) {
  const int blk = blockIdx.x;  // 16 = b*8+h
  const int b = blk >> 3, h = blk & 7;
  const int tid = threadIdx.x;
  __shared__ float Sl[128 * 132];   // S[j][c] at j*132+c (pad vs bank conflicts)
  __shared__ float Tkl[16 * 132];
  __shared__ float Tql[16 * 132];

  for (int idx = tid; idx < 16384; idx += 256) {
    float s = 0.f;
#pragma unroll
    for (int sl = 0; sl < 8; ++sl)
      s += part2[((size_t)(b * 8 + sl) << 14) + idx];
    Sl[(idx >> 7) * 132 + (idx & 127)] = s;
  }
  __syncthreads();

  // T[d][c] = sum_cc W[h*16+d][cc] * S[c][cc]
  const int c = tid & 127, hl = tid >> 7;
#pragma unroll
  for (int t = 0; t < 2; ++t) {
    const float* W = (t ? Wq : Wk);
    float* Tl = (t ? Tql : Tkl);
    const f32x4* s4 = (const f32x4*)(Sl + c * 132);
#pragma unroll
    for (int rep = 0; rep < 8; ++rep) {
      const int d = rep * 2 + hl;
      const f32x4* w4 = (const f32x4*)(W + (h * 16 + d) * 128);
      float v = 0.f;
#pragma unroll 8
      for (int q = 0; q < 32; ++q) {
        const f32x4 a = w4[q], s = s4[q];
        v += a[0] * s[0] + a[1] * s[1] + a[2] * s[2] + a[3] * s[3];
      }
      Tl[d * 132 + c] = v;
    }
  }
  __syncthreads();

  const int e = tid & 15, d = tid >> 4;
  const f32x4* tk4 = (const f32x4*)(Tkl + d * 132);
  const f32x4* wq4 = (const f32x4*)(Wq + (h * 16 + e) * 128);
  float g = 0.f;
#pragma unroll 8
  for (int q = 0; q < 32; ++q) {
    const f32x4 a = tk4[q], w = wq4[q];
    g += a[0] * w[0] + a[1] * w[1] + a[2] * w[2] + a[3] * w[3];
  }

  __shared__ float sqk[16], sqq[16];
  if (e == 0) {
    const f32x4* wk4 = (const f32x4*)(Wk + (h * 16 + d) * 128);
    float s = 0.f;
    for (int q = 0; q < 32; ++q) {
      const f32x4 a = tk4[q], w = wk4[q];
      s += a[0] * w[0] + a[1] * w[1] + a[2] * w[2] + a[3] * w[3];
    }
    sqk[d] = s;
  }
  if (d == 0) {
    const f32x4* tq4 = (const f32x4*)(Tql + e * 132);
    float s = 0.f;
    for (int q = 0; q < 32; ++q) {
      const f32x4 a = tq4[q], w = wq4[q];
      s += a[0] * w[0] + a[1] * w[1] + a[2] * w[2] + a[3] * w[3];
    }
    sqq[e] = s;
  }
  __syncthreads();

  const float nk = fmaxf(sqrtf(fmaxf(sqk[d], 0.f)), 1e-12f);
  const float nq = fmaxf(sqrtf(fmaxf(sqq[e], 0.f)), 1e-12f);
  float pre = g / (nk * nq) * resc[h];

  float mx = pre;
#pragma unroll
  for (int m = 1; m < 16; m <<= 1) mx = fmaxf(mx, __shfl_xor(mx, m, 64));
  const float p = expf(pre - mx);
  float sum = p;
#pragma unroll
  for (int m = 1; m < 16; m <<= 1) sum += __shfl_xor(sum, m, 64);
  attn[blk * 256 + tid] = p / sum;
}

// ---------------------------------------------------------------------------
// K3c: P[b] = Wp * blockdiag(attn[b]) * Wv, stored bf16 (rounding error of P
// contributes <2e-3 to the final absmax).
// ---------------------------------------------------------------------------
__global__ __launch_bounds__(256) void k3_p(const float* __restrict__ attn,
                                            const float* __restrict__ Wp,
                                            const float* __restrict__ Wv,
                                            bf16_t* __restrict__ Phi) {
  const int blk = blockIdx.x;  // 256 = b*128 + row
  const int b = blk >> 7, rrow = blk & 127;
  const int tid = threadIdx.x;
  __shared__ float M[128];
  if (tid < 128) {
    const int h = tid >> 4, e = tid & 15;
    const float* A = attn + (size_t)(b * 8 + h) * 256;
    const float* wp = Wp + rrow * 128 + h * 16;
    float m = 0.f;
#pragma unroll
    for (int d = 0; d < 16; ++d) m += wp[d] * A[d * 16 + e];
    M[tid] = m;
  }
  __syncthreads();
  if (tid < 128) {
    const int c = tid;
    float p = 0.f;
#pragma unroll 4
    for (int j = 0; j < 128; ++j) p += M[j] * Wv[j * 128 + c];
    Phi[((size_t)b << 14) + rrow * 128 + c] = (bf16_t)p;
  }
}

// ---------------------------------------------------------------------------
// K4: out[b] = P_b * X_b + bp, fp32 out, native [b][c][s][h][w] layout.
// grid 1536 = b(2) x 64-token tiles(768). Wave: 16 tokens x 128 couts.
// ---------------------------------------------------------------------------
__global__ __launch_bounds__(256) void k4_out(const float* __restrict__ x,
                                              const bf16_t* __restrict__ Phi,
                                              const float* __restrict__ bp,
                                              float* __restrict__ out) {
  const int blk = blockIdx.x;
  const int b = blk / 768, tg = blk % 768;
  const float* Xb = x + (size_t)b * CDIM * NTOK;
  const bf16_t* Ph = Phi + ((size_t)b << 14);
  float* Ob = out + (size_t)b * CDIM * NTOK;
  const int tid = threadIdx.x, wave = tid >> 6, lane = tid & 63;
  const int r = lane & 15, quad = lane >> 4;
  const int tok0 = tg * 64 + wave * 16;

  f32x4 acc[8];
#pragma unroll
  for (int m = 0; m < 8; ++m) acc[m] = (f32x4){0.f, 0.f, 0.f, 0.f};

#pragma unroll
  for (int kb = 0; kb < 128; kb += 32) {
    bf16x8 ah[8];
#pragma unroll
    for (int m = 0; m < 8; ++m)
      ah[m] = *(const bf16x8*)(Ph + (16 * m + r) * 128 + kb + quad * 8);
    const float* base = Xb + (size_t)(kb + quad * 8) * NTOK + tok0 + r;
    bf16x8 bh;
#pragma unroll
    for (int i = 0; i < 8; ++i) bh[i] = (bf16_t)base[(size_t)i * NTOK];
#pragma unroll
    for (int m = 0; m < 8; ++m)
      acc[m] = __builtin_amdgcn_mfma_f32_16x16x32_bf16(ah[m], bh, acc[m], 0, 0, 0);
  }

#pragma unroll
  for (int m = 0; m < 8; ++m) {
#pragma unroll
    for (int reg = 0; reg < 4; ++reg) {
      const int row = m * 16 + quad * 4 + reg;
      Ob[(size_t)row * NTOK + tok0 + r] = acc[m][reg] + bp[row];
    }
  }
}

extern "C" void kernel_launch(void* const* d_in, const int* in_sizes, int n_in,
                              void* d_out, int out_size, void* d_ws, size_t ws_size,
                              hipStream_t stream) {
  const float* x    = (const float*)d_in[0];
  const float* Wq   = (const float*)d_in[1];
  const float* Wk   = (const float*)d_in[2];
  const float* Wv   = (const float*)d_in[3];
  const float* Wp   = (const float*)d_in[4];
  const float* bp   = (const float*)d_in[5];
  const float* resc = (const float*)d_in[6];
  float* out = (float*)d_out;

  // Small scratch in d_ws (proven >= 540 KB in round 3; we use 82 KB).
  char* ws = (char*)d_ws;
  float*  attn = (float*)(ws + 0);        // 16384 B
  bf16_t* Phi  = (bf16_t*)(ws + 16384);   // 65536 B
  // Big scratch inside d_out (50.3 MB): partials 33.55 MB + part2 1 MB.
  // All consumed (k2a, k3_ta) before k4 overwrites d_out with the output.
  float* part  = (float*)d_out;                              // 33,554,432 B
  float* part2 = (float*)((char*)d_out + 33554432);          //  1,048,576 B

  k1_gram<<<1024, 256, 0, stream>>>(x, part);
  k2a_reduce<<<1024, 256, 0, stream>>>(part, part2);
  k3_ta<<<16, 256, 0, stream>>>(part2, Wk, Wq, resc, attn);
  k3_p<<<256, 256, 0, stream>>>(attn, Wp, Wv, Phi);
  k4_out<<<1536, 256, 0, stream>>>(x, Phi, bp, out);
}

// Round 5
// 179.467 us; speedup vs baseline: 1.3456x; 1.3456x over previous
//
#include <hip/hip_runtime.h>
#include <hip/hip_bf16.h>

typedef __bf16 bf16_t;
typedef __bf16 bf16x8 __attribute__((ext_vector_type(8)));
typedef float f32x4 __attribute__((ext_vector_type(4)));

#define NTOK 49152   // s*h*w = 3*128*128 tokens per batch
#define CDIM 128
#define CHUNKS 192   // split-K chunks for the Gram
#define KT 256       // tokens per chunk
#define STEPS 8      // KT/32

__device__ inline f32x4 mfma16(bf16x8 a, bf16x8 b, f32x4 c) {
  return __builtin_amdgcn_mfma_f32_16x16x32_bf16(a, b, c, 0, 0, 0);
}

// ---------------------------------------------------------------------------
// K1: per-batch token Gram S = X X^T, split-K fp32 partials.
// grid 384 = b(2) x chunk(192). Block: full 128x128 output over 256 tokens.
// X tile (128 ch x 32 tok) staged fp32->bf16 into LDS in FRAGMENT ORDER:
// 16B chunk index = g*64 + lane (g = ch>>4, lane = quad*16 + r), so frag
// reads are lane-consecutive ds_read_b128 (conflict-free). A-frags are a
// subset of the B-frags (wave w: frag[2w], frag[2w+1]) -- zero extra loads.
// Double-buffered, 1 barrier/step; next tile's global loads issued before
// the MFMAs so HBM latency overlaps compute.
// ---------------------------------------------------------------------------
__global__ __launch_bounds__(256) void k1_gram(const float* __restrict__ x,
                                               float* __restrict__ part) {
  const int blk = blockIdx.x;
  const int b = blk / CHUNKS, chunk = blk % CHUNKS;
  const float* Xb = x + (size_t)b * CDIM * NTOK;
  const int tid = threadIdx.x, wave = tid >> 6, lane = tid & 63;
  const int r = lane & 15, quad = lane >> 4;

  __shared__ __align__(16) bf16_t tile[2][128 * 32];  // frag-ordered, 8 KB each

  // Staging map: thread t -> ch = t>>1, half = t&1 (16 toks each).
  const int sch = tid >> 1, shalf = tid & 1;
  const float* gsrc = Xb + (size_t)sch * NTOK + chunk * KT + shalf * 16;

  f32x4 st[4];
#define STAGE_LOAD(step)                                   \
  {                                                        \
    const float* p_ = gsrc + (step) * 32;                  \
    st[0] = *(const f32x4*)(p_ + 0);                       \
    st[1] = *(const f32x4*)(p_ + 4);                       \
    st[2] = *(const f32x4*)(p_ + 8);                       \
    st[3] = *(const f32x4*)(p_ + 12);                      \
  }
#define STAGE_WRITE(buf)                                              \
  {                                                                   \
    bf16_t* t_ = &tile[buf][0];                                       \
    _Pragma("unroll")                                                 \
    for (int j_ = 0; j_ < 16; ++j_) {                                 \
      const int tok_ = shalf * 16 + j_;                               \
      const int c16_ = ((sch >> 4) << 6) + ((tok_ >> 3) << 4) + (sch & 15); \
      t_[c16_ * 8 + (tok_ & 7)] = (bf16_t)st[j_ >> 2][j_ & 3];        \
    }                                                                 \
  }

  f32x4 acc[2][8];
#pragma unroll
  for (int t = 0; t < 2; ++t)
#pragma unroll
    for (int j = 0; j < 8; ++j) acc[t][j] = (f32x4){0.f, 0.f, 0.f, 0.f};

  STAGE_LOAD(0);
  STAGE_WRITE(0);
  __syncthreads();

  for (int k = 0; k < STEPS; ++k) {
    const int buf = k & 1;
    if (k + 1 < STEPS) STAGE_LOAD(k + 1);          // issue early (overlap)
    bf16x8 frag[8];
#pragma unroll
    for (int g = 0; g < 8; ++g)
      frag[g] = *(const bf16x8*)&tile[buf][(g * 64 + lane) * 8];
    bf16x8 a0, a1;                                  // wave-uniform select
    if (wave == 0)      { a0 = frag[0]; a1 = frag[1]; }
    else if (wave == 1) { a0 = frag[2]; a1 = frag[3]; }
    else if (wave == 2) { a0 = frag[4]; a1 = frag[5]; }
    else                { a0 = frag[6]; a1 = frag[7]; }
#pragma unroll
    for (int j = 0; j < 8; ++j) {
      acc[0][j] = mfma16(a0, frag[j], acc[0][j]);
      acc[1][j] = mfma16(a1, frag[j], acc[1][j]);
    }
    if (k + 1 < STEPS) STAGE_WRITE(1 - buf);        // safe: 1-buf last read at k-1
    __syncthreads();
  }
#undef STAGE_LOAD
#undef STAGE_WRITE

  float* pb = part + ((size_t)(b * CHUNKS + chunk) << 14);
#pragma unroll
  for (int t = 0; t < 2; ++t) {
#pragma unroll
    for (int j = 0; j < 8; ++j) {
#pragma unroll
      for (int reg = 0; reg < 4; ++reg) {
        const int row = wave * 32 + t * 16 + quad * 4 + reg;  // C/D: row=quad*4+reg
        const int col = 16 * j + r;                            // col=lane&15
        pb[row * 128 + col] = acc[t][j][reg];
      }
    }
  }
}

// ---------------------------------------------------------------------------
// K2a: reduce 192 chunks -> 8 slice-partials of 24 chunks each. f32x4, high MLP.
// ---------------------------------------------------------------------------
__global__ __launch_bounds__(256) void k2a_reduce(const float* __restrict__ part,
                                                  float* __restrict__ part2) {
  const int gid = blockIdx.x * 256 + threadIdx.x;  // 65536 threads
  const int e4 = gid & 4095, sl = (gid >> 12) & 7, b = gid >> 15;
  const float* p = part + ((size_t)(b * CHUNKS + sl * 24) << 14) + e4 * 4;
  f32x4 s = (f32x4){0.f, 0.f, 0.f, 0.f};
#pragma unroll 8
  for (int i = 0; i < 24; ++i) s += *(const f32x4*)(p + ((size_t)i << 14));
  *(f32x4*)(part2 + ((size_t)(b * 8 + sl) << 14) + e4 * 4) = s;
}

// ---------------------------------------------------------------------------
// K2b: sum 8 slices -> S[2][128][128] fp32
// ---------------------------------------------------------------------------
__global__ __launch_bounds__(256) void k2b_reduce(const float* __restrict__ part2,
                                                  float* __restrict__ S) {
  const int gid = blockIdx.x * 256 + threadIdx.x;  // 8192 threads
  const int e4 = gid & 4095, b = gid >> 12;
  f32x4 s = (f32x4){0.f, 0.f, 0.f, 0.f};
#pragma unroll
  for (int sl = 0; sl < 8; ++sl)
    s += *(const f32x4*)(part2 + ((size_t)(b * 8 + sl) << 14) + e4 * 4);
  *(f32x4*)(S + ((size_t)b << 14) + e4 * 4) = s;
}

// ---------------------------------------------------------------------------
// K3a: T[b][t][i][j] = sum_c W_t[i][c] * S_b[j][c]  (t=0:Wk, 1:Wq; S symmetric)
// ---------------------------------------------------------------------------
__global__ __launch_bounds__(256) void k3_t(const float* __restrict__ S,
                                            const float* __restrict__ Wk,
                                            const float* __restrict__ Wq,
                                            float* __restrict__ Tm) {
  const int idx = blockIdx.x * 256 + threadIdx.x;  // 0..65535
  const int j = idx & 127, i = (idx >> 7) & 127, t = (idx >> 14) & 1, b = idx >> 15;
  const f32x4* w4 = (const f32x4*)((t ? Wq : Wk) + i * 128);
  const f32x4* s4 = (const f32x4*)(S + (b << 14) + j * 128);
  float s = 0.f;
#pragma unroll 8
  for (int q = 0; q < 32; ++q) {
    const f32x4 a = w4[q], v = s4[q];
    s += a[0] * v[0] + a[1] * v[1] + a[2] * v[2] + a[3] * v[3];
  }
  Tm[idx] = s;
}

// ---------------------------------------------------------------------------
// K3b: per (b,head): G = Wk S Wq^T, norms from diagonals, softmax -> attn
// ---------------------------------------------------------------------------
__global__ __launch_bounds__(256) void k3_attn(const float* __restrict__ Tm,
                                               const float* __restrict__ Wk,
                                               const float* __restrict__ Wq,
                                               const float* __restrict__ resc,
                                               float* __restrict__ attn) {
  const int blk = blockIdx.x;  // 16 = b*8+h
  const int b = blk >> 3, h = blk & 7;
  const int tid = threadIdx.x, d = tid >> 4, e = tid & 15;
  const float* Tk = Tm + (size_t)(b * 2 + 0) * 16384;
  const float* Tq = Tm + (size_t)(b * 2 + 1) * 16384;

  const float* tkrow = Tk + (h * 16 + d) * 128;
  const float* wqrow = Wq + (h * 16 + e) * 128;
  float g = 0.f;
#pragma unroll 4
  for (int c = 0; c < 128; ++c) g += tkrow[c] * wqrow[c];

  __shared__ float sqk[16], sqq[16];
  if (e == 0) {
    const float* wkrow = Wk + (h * 16 + d) * 128;
    float s = 0.f;
    for (int c = 0; c < 128; ++c) s += tkrow[c] * wkrow[c];
    sqk[d] = s;
  }
  if (d == 0) {
    const float* tqrow = Tq + (h * 16 + e) * 128;
    float s = 0.f;
    for (int c = 0; c < 128; ++c) s += tqrow[c] * wqrow[c];
    sqq[e] = s;
  }
  __syncthreads();

  const float nk = fmaxf(sqrtf(fmaxf(sqk[d], 0.f)), 1e-12f);
  const float nq = fmaxf(sqrtf(fmaxf(sqq[e], 0.f)), 1e-12f);
  float pre = g / (nk * nq) * resc[h];

  float mx = pre;
#pragma unroll
  for (int m = 1; m < 16; m <<= 1) mx = fmaxf(mx, __shfl_xor(mx, m, 64));
  const float p = expf(pre - mx);
  float sum = p;
#pragma unroll
  for (int m = 1; m < 16; m <<= 1) sum += __shfl_xor(sum, m, 64);
  attn[blk * 256 + tid] = p / sum;
}

// ---------------------------------------------------------------------------
// K3c: P[b] = Wp * blockdiag(attn[b]) * Wv, stored bf16 (P rounding adds <2e-3).
// ---------------------------------------------------------------------------
__global__ __launch_bounds__(256) void k3_p(const float* __restrict__ attn,
                                            const float* __restrict__ Wp,
                                            const float* __restrict__ Wv,
                                            bf16_t* __restrict__ Phi) {
  const int blk = blockIdx.x;  // 256 = b*128 + row
  const int b = blk >> 7, rrow = blk & 127;
  const int tid = threadIdx.x;
  __shared__ float M[128];
  if (tid < 128) {
    const int h = tid >> 4, e = tid & 15;
    const float* A = attn + (size_t)(b * 8 + h) * 256;
    const float* wp = Wp + rrow * 128 + h * 16;
    float m = 0.f;
#pragma unroll
    for (int d = 0; d < 16; ++d) m += wp[d] * A[d * 16 + e];
    M[tid] = m;
  }
  __syncthreads();
  if (tid < 128) {
    const int c = tid;
    float p = 0.f;
#pragma unroll 4
    for (int j = 0; j < 128; ++j) p += M[j] * Wv[j * 128 + c];
    Phi[((size_t)b << 14) + rrow * 128 + c] = (bf16_t)p;
  }
}

// ---------------------------------------------------------------------------
// K4: out[b] = P_b * X_b + bp, fp32 out, native layout. grid 1536 = b x 768
// tiles of 64 tokens. X tile (128 ch x 64 tok) staged fp32->bf16 into LDS in
// fragment order (chunk = (ch>>5)*256 + (tok>>4)*64 + ((ch>>3)&3)*16 +
// (tok&15)), killing the 8-way scalar gather. K=128 fully resident; one sync.
// ---------------------------------------------------------------------------
__global__ __launch_bounds__(256) void k4_out(const float* __restrict__ x,
                                              const bf16_t* __restrict__ Phi,
                                              const float* __restrict__ bp,
                                              float* __restrict__ out) {
  const int blk = blockIdx.x;
  const int b = blk / 768, tg = blk % 768;
  const float* Xb = x + (size_t)b * CDIM * NTOK;
  const bf16_t* Ph = Phi + ((size_t)b << 14);
  float* Ob = out + (size_t)b * CDIM * NTOK;
  const int tid = threadIdx.x, wave = tid >> 6, lane = tid & 63;
  const int r = lane & 15, quad = lane >> 4;
  const int tok0 = tg * 64;

  __shared__ __align__(16) bf16_t tile[128 * 64];  // frag-ordered, 16 KB

  // Stage: thread t -> ch = t>>1, half = t&1 (32 toks each), coalesced f32x4.
  {
    const int sch = tid >> 1, shalf = tid & 1;
    const float* p = Xb + (size_t)sch * NTOK + tok0 + shalf * 32;
    f32x4 st[8];
#pragma unroll
    for (int q = 0; q < 8; ++q) st[q] = *(const f32x4*)(p + q * 4);
    const int chunk_hi = ((sch >> 5) << 8) + (((sch >> 3) & 3) << 4);
    const int ei = sch & 7;
#pragma unroll
    for (int j = 0; j < 32; ++j) {
      const int tok = shalf * 32 + j;
      const int chunk = chunk_hi + ((tok >> 4) << 6) + (tok & 15);
      tile[chunk * 8 + ei] = (bf16_t)st[j >> 2][j & 3];
    }
  }
  __syncthreads();

  f32x4 acc[8];
#pragma unroll
  for (int m = 0; m < 8; ++m) acc[m] = (f32x4){0.f, 0.f, 0.f, 0.f};

#pragma unroll
  for (int step = 0; step < 4; ++step) {  // kb = step*32
    const bf16x8 bfr = *(const bf16x8*)&tile[(step * 256 + wave * 64 + lane) * 8];
#pragma unroll
    for (int m = 0; m < 8; ++m) {
      const bf16x8 ah = *(const bf16x8*)(Ph + (16 * m + r) * 128 + step * 32 + quad * 8);
      acc[m] = mfma16(ah, bfr, acc[m]);
    }
  }

  const int wtok = tok0 + wave * 16;
#pragma unroll
  for (int m = 0; m < 8; ++m) {
#pragma unroll
    for (int reg = 0; reg < 4; ++reg) {
      const int row = m * 16 + quad * 4 + reg;
      Ob[(size_t)row * NTOK + wtok + r] = acc[m][reg] + bp[row];
    }
  }
}

extern "C" void kernel_launch(void* const* d_in, const int* in_sizes, int n_in,
                              void* d_out, int out_size, void* d_ws, size_t ws_size,
                              hipStream_t stream) {
  const float* x    = (const float*)d_in[0];
  const float* Wq   = (const float*)d_in[1];
  const float* Wk   = (const float*)d_in[2];
  const float* Wv   = (const float*)d_in[3];
  const float* Wp   = (const float*)d_in[4];
  const float* bp   = (const float*)d_in[5];
  const float* resc = (const float*)d_in[6];
  float* out = (float*)d_out;

  // Small scratch in d_ws (layout proven safe in round 3, <= 442 KB used).
  char* ws = (char*)d_ws;
  float*  S    = (float*)(ws + 0);        // 131072 B
  float*  Tm   = (float*)(ws + 131072);   // 262144 B
  float*  attn = (float*)(ws + 393216);   //  16384 B
  bf16_t* Phi  = (bf16_t*)(ws + 409600);  //  65536 B
  // Big scratch inside d_out (50.3 MB): partials 24 MB + part2 1 MB, both
  // consumed (k2a/k2b) before k4 overwrites d_out with the real output.
  float* part  = (float*)d_out;                      // 24 MB
  float* part2 = (float*)((char*)d_out + 25165824);  //  1 MB

  k1_gram<<<2 * CHUNKS, 256, 0, stream>>>(x, part);
  k2a_reduce<<<256, 256, 0, stream>>>(part, part2);
  k2b_reduce<<<32, 256, 0, stream>>>(part2, S);
  k3_t<<<256, 256, 0, stream>>>(S, Wk, Wq, Tm);
  k3_attn<<<16, 256, 0, stream>>>(Tm, Wk, Wq, resc, attn);
  k3_p<<<256, 256, 0, stream>>>(attn, Wp, Wv, Phi);
  k4_out<<<1536, 256, 0, stream>>>(x, Phi, bp, out);
}